// Round 2
// baseline (10893.286 us; speedup 1.0000x reference)
//
#include <hip/hip_runtime.h>

// EncoderDecoderLSTM persistent kernel, round 2.
// Weights live in VGPRs (per-thread slices), activations broadcast from LDS.
// 256 blocks x 512 threads; block owns 32 batch rows for all 336+168 steps.
// Thread (jg = tid>>2, q = tid&3): gate-rows {jg, jg+128}, m-slice [q*16, q*16+16).
// Quad shfl_xor reduce over q; gates -> LDS; pointwise threads (pr=tid>>4,
// pc=(tid&15)*4) own c-state in registers and write h back to LDS.

#define NB 256
#define NT 512
#define TT 336
#define HZN 168

__device__ __forceinline__ float fexp(float v){
  return __builtin_amdgcn_exp2f(v * 1.44269504088896340736f);
}
__device__ __forceinline__ float sigm(float v){
  return __builtin_amdgcn_rcpf(1.0f + fexp(-v));
}
__device__ __forceinline__ float tanh_(float v){
  return 1.0f - 2.0f * __builtin_amdgcn_rcpf(1.0f + fexp(2.0f * v));
}

// load thread's slice of a [256][64] matrix: rows {jg, jg+128}, cols [q16,q16+16)
__device__ __forceinline__ void loadW(float4 w[2][4], const float* __restrict__ M,
                                      int jg, int q16){
  #pragma unroll
  for (int g=0; g<2; g++)
    #pragma unroll
    for (int mc=0; mc<4; mc++)
      w[g][mc] = *(const float4*)(M + (size_t)(jg + g*128)*64 + q16 + mc*4);
}

// a0 += dot(w[0], in[0..16)); a1 += dot(w[1], in[0..16))  (two partial chains each)
__device__ __forceinline__ void dot16x2(float& a0, float& a1,
                                        const float4 w[2][4],
                                        const float* __restrict__ in){
  float4 v0 = *(const float4*)(in);
  float4 v1 = *(const float4*)(in+4);
  float4 v2 = *(const float4*)(in+8);
  float4 v3 = *(const float4*)(in+12);
  float p0, p1, s0, s1;
  p0 = w[0][0].x*v0.x; p0 = fmaf(w[0][0].y, v0.y, p0);
  p0 = fmaf(w[0][0].z, v0.z, p0); p0 = fmaf(w[0][0].w, v0.w, p0);
  p0 = fmaf(w[0][1].x, v1.x, p0); p0 = fmaf(w[0][1].y, v1.y, p0);
  p0 = fmaf(w[0][1].z, v1.z, p0); p0 = fmaf(w[0][1].w, v1.w, p0);
  s0 = w[0][2].x*v2.x; s0 = fmaf(w[0][2].y, v2.y, s0);
  s0 = fmaf(w[0][2].z, v2.z, s0); s0 = fmaf(w[0][2].w, v2.w, s0);
  s0 = fmaf(w[0][3].x, v3.x, s0); s0 = fmaf(w[0][3].y, v3.y, s0);
  s0 = fmaf(w[0][3].z, v3.z, s0); s0 = fmaf(w[0][3].w, v3.w, s0);
  p1 = w[1][0].x*v0.x; p1 = fmaf(w[1][0].y, v0.y, p1);
  p1 = fmaf(w[1][0].z, v0.z, p1); p1 = fmaf(w[1][0].w, v0.w, p1);
  p1 = fmaf(w[1][1].x, v1.x, p1); p1 = fmaf(w[1][1].y, v1.y, p1);
  p1 = fmaf(w[1][1].z, v1.z, p1); p1 = fmaf(w[1][1].w, v1.w, p1);
  s1 = w[1][2].x*v2.x; s1 = fmaf(w[1][2].y, v2.y, s1);
  s1 = fmaf(w[1][2].z, v2.z, s1); s1 = fmaf(w[1][2].w, v2.w, s1);
  s1 = fmaf(w[1][3].x, v3.x, s1); s1 = fmaf(w[1][3].y, v3.y, s1);
  s1 = fmaf(w[1][3].z, v3.z, s1); s1 = fmaf(w[1][3].w, v3.w, s1);
  a0 += p0 + s0;
  a1 += p1 + s1;
}

// finalize one row's two gate values: quad reduce + LDS write
__device__ __forceinline__ void red_write(float* __restrict__ gb, int rr, int jg,
                                          int q, float a0, float a1){
  a0 += __shfl_xor(a0, 1); a0 += __shfl_xor(a0, 2);
  a1 += __shfl_xor(a1, 1); a1 += __shfl_xor(a1, 2);
  if (q == 0)      gb[rr*256 + jg]       = a0;
  else if (q == 1) gb[rr*256 + 128 + jg] = a1;
}

// gates = bias + wX . inX + wY . inY   (32 rows)
__device__ __forceinline__ void mm2(float* __restrict__ gb,
  const float* __restrict__ inX, const float* __restrict__ inY,
  const float4 wX[2][4], const float4 wY[2][4],
  float b0, float b1, int jg, int q, int q16)
{
  #pragma unroll 8
  for (int rr=0; rr<32; rr++){
    float a0 = (q==0) ? b0 : 0.f;
    float a1 = (q==0) ? b1 : 0.f;
    dot16x2(a0, a1, wX, inX + rr*64 + q16);
    dot16x2(a0, a1, wY, inY + rr*64 + q16);
    red_write(gb, rr, jg, q, a0, a1);
  }
}

// gates = bias + wY . inY   (decoder step 0: x-input is zero)
__device__ __forceinline__ void mm1(float* __restrict__ gb,
  const float* __restrict__ inY, const float4 wY[2][4],
  float b0, float b1, int jg, int q, int q16)
{
  #pragma unroll 8
  for (int rr=0; rr<32; rr++){
    float a0 = (q==0) ? b0 : 0.f;
    float a1 = (q==0) ? b1 : 0.f;
    dot16x2(a0, a1, wY, inY + rr*64 + q16);
    red_write(gb, rr, jg, q, a0, a1);
  }
}

// encoder layer0: gates = bias + wx*x[r,t] + wY . inY
__device__ __forceinline__ void mm1x(float* __restrict__ gb,
  const float* __restrict__ inY, const float4 wY[2][4],
  const float* __restrict__ xs, int t,
  float wx0, float wx1, float b0, float b1, int jg, int q, int q16)
{
  #pragma unroll 8
  for (int rr=0; rr<32; rr++){
    float xr = xs[rr*336 + t];
    float a0 = (q==0) ? fmaf(wx0, xr, b0) : 0.f;
    float a1 = (q==0) ? fmaf(wx1, xr, b1) : 0.f;
    dot16x2(a0, a1, wY, inY + rr*64 + q16);
    red_write(gb, rr, jg, q, a0, a1);
  }
}

__device__ __forceinline__ float upd(float i, float f, float g, float o, float& c){
  float ig = sigm(i), fg = sigm(f), gg = tanh_(g), og = sigm(o);
  c = fmaf(fg, c, ig*gg);
  return og * tanh_(c);
}

__device__ __forceinline__ float4 pointwise(const float* __restrict__ gb,
                                            float* __restrict__ hb,
                                            float4& cv, int pr, int pc){
  const float* gr = gb + pr*256 + pc;
  float4 gi = *(const float4*)(gr);
  float4 gf = *(const float4*)(gr + 64);
  float4 gg = *(const float4*)(gr + 128);
  float4 go = *(const float4*)(gr + 192);
  float4 h;
  h.x = upd(gi.x, gf.x, gg.x, go.x, cv.x);
  h.y = upd(gi.y, gf.y, gg.y, go.y, cv.y);
  h.z = upd(gi.z, gf.z, gg.z, go.z, cv.z);
  h.w = upd(gi.w, gf.w, gg.w, go.w, cv.w);
  *(float4*)(hb + pr*64 + pc) = h;
  return h;
}

__global__ __launch_bounds__(NT, 2)
void edlstm_kernel(const float* __restrict__ x,
  const float* __restrict__ eWih0, const float* __restrict__ eWhh0,
  const float* __restrict__ ebih0, const float* __restrict__ ebhh0,
  const float* __restrict__ eWih1, const float* __restrict__ eWhh1,
  const float* __restrict__ ebih1, const float* __restrict__ ebhh1,
  const float* __restrict__ dWih0, const float* __restrict__ dWhh0,
  const float* __restrict__ dbih0, const float* __restrict__ dbhh0,
  const float* __restrict__ dWih1, const float* __restrict__ dWhh1,
  const float* __restrict__ dbih1, const float* __restrict__ dbhh1,
  const float* __restrict__ fcW, const float* __restrict__ fcb,
  float* __restrict__ out)
{
  extern __shared__ float sm[];
  float* h0b = sm;             // [32][64]
  float* h1b = sm + 2048;      // [32][64]
  float* g0  = sm + 4096;      // [32][256]
  float* g1  = sm + 12288;     // [32][256]
  float* xs  = sm + 20480;     // [32][336]

  const int tid = threadIdx.x;
  const int q   = tid & 3;
  const int q16 = q * 16;
  const int jg  = tid >> 2;        // 0..127
  const int pr  = tid >> 4;        // pointwise row 0..31
  const int pc  = (tid & 15) * 4;  // pointwise col base
  const int brow0 = blockIdx.x * 32;

  // ---- prologue: stage x rows into LDS, zero h ----
  #pragma unroll
  for (int k=0; k<6; k++){
    int idx = k*NT + tid;          // 2688 float4 total (32 rows x 84)
    if (idx < 2688){
      int row = idx / 84;
      int c   = idx - row*84;
      *(float4*)(xs + row*336 + c*4) =
        *(const float4*)(x + (size_t)(brow0+row)*336 + c*4);
    }
  }
  #pragma unroll
  for (int k=0; k<8; k++) h0b[k*NT + tid] = 0.f;   // h0b+h1b contiguous 4096

  // ---- encoder weights into VGPRs ----
  float4 wA[2][4], wB[2][4], wC[2][4];
  loadW(wA, eWhh0, jg, q16);
  loadW(wB, eWih1, jg, q16);
  loadW(wC, eWhh1, jg, q16);
  float wx0 = eWih0[jg], wx1 = eWih0[jg+128];
  float be0a = ebih0[jg]     + ebhh0[jg];
  float be0b = ebih0[jg+128] + ebhh0[jg+128];
  float be1a = ebih1[jg]     + ebhh1[jg];
  float be1b = ebih1[jg+128] + ebhh1[jg+128];
  float4 fw = *(const float4*)(fcW + pc);
  float fb = fcb[0];
  float4 c0v = {0.f,0.f,0.f,0.f};
  float4 c1v = {0.f,0.f,0.f,0.f};
  __syncthreads();

  // ---------------- encoder: 336 steps ----------------
  for (int t=0; t<TT; t++){
    mm1x(g0, h0b, wA, xs, t, wx0, wx1, be0a, be0b, jg, q, q16);
    __syncthreads();
    pointwise(g0, h0b, c0v, pr, pc);
    __syncthreads();
    mm2(g1, h0b, h1b, wB, wC, be1a, be1b, jg, q, q16);
    __syncthreads();
    pointwise(g1, h1b, c1v, pr, pc);
    // no barrier: next phase0 touches only h0b/g0/xs, >=2 barriers before h1b read
  }
  __syncthreads();

  // ---- decoder weights into VGPRs (reuse + one extra array) ----
  float4 wD[2][4];
  loadW(wA, dWih0, jg, q16);
  loadW(wB, dWhh0, jg, q16);
  loadW(wC, dWih1, jg, q16);
  loadW(wD, dWhh1, jg, q16);
  float bd0a = dbih0[jg]     + dbhh0[jg];
  float bd0b = dbih0[jg+128] + dbhh0[jg+128];
  float bd1a = dbih1[jg]     + dbhh1[jg];
  float bd1b = dbih1[jg+128] + dbhh1[jg+128];

  // ---------------- decoder: 168 autoregressive steps ----------------
  for (int s=0; s<HZN; s++){
    if (s == 0)
      mm1(g0, h0b, wB, bd0a, bd0b, jg, q, q16);                 // xin = 0
    else
      mm2(g0, h1b, h0b, wA, wB, bd0a, bd0b, jg, q, q16);        // Wih0.h1 + Whh0.h0
    __syncthreads();
    pointwise(g0, h0b, c0v, pr, pc);
    __syncthreads();
    mm2(g1, h0b, h1b, wC, wD, bd1a, bd1b, jg, q, q16);          // Wih1.h0 + Whh1.h1
    __syncthreads();
    float4 h1v = pointwise(g1, h1b, c1v, pr, pc);
    // fc: reduce over 16 pc-lanes
    float p = h1v.x*fw.x + h1v.y*fw.y + h1v.z*fw.z + h1v.w*fw.w;
    p += __shfl_xor(p, 1); p += __shfl_xor(p, 2);
    p += __shfl_xor(p, 4); p += __shfl_xor(p, 8);
    if ((tid & 15) == 0)
      out[(size_t)(brow0 + pr)*HZN + s] = p + fb;
    __syncthreads();   // protect h1b for next phaseA
  }
}

extern "C" void kernel_launch(void* const* d_in, const int* in_sizes, int n_in,
                              void* d_out, int out_size, void* d_ws, size_t ws_size,
                              hipStream_t stream)
{
  (void)in_sizes; (void)n_in; (void)d_ws; (void)ws_size; (void)out_size;
  const float* x     = (const float*)d_in[0];
  const float* eWih0 = (const float*)d_in[1];
  const float* eWhh0 = (const float*)d_in[2];
  const float* ebih0 = (const float*)d_in[3];
  const float* ebhh0 = (const float*)d_in[4];
  const float* eWih1 = (const float*)d_in[5];
  const float* eWhh1 = (const float*)d_in[6];
  const float* ebih1 = (const float*)d_in[7];
  const float* ebhh1 = (const float*)d_in[8];
  const float* dWih0 = (const float*)d_in[9];
  const float* dWhh0 = (const float*)d_in[10];
  const float* dbih0 = (const float*)d_in[11];
  const float* dbhh0 = (const float*)d_in[12];
  const float* dWih1 = (const float*)d_in[13];
  const float* dWhh1 = (const float*)d_in[14];
  const float* dbih1 = (const float*)d_in[15];
  const float* dbhh1 = (const float*)d_in[16];
  const float* fcW   = (const float*)d_in[17];
  const float* fcb   = (const float*)d_in[18];
  float* out = (float*)d_out;

  const int lds_bytes = (2*2048 + 2*8192 + 32*336) * 4;   // 124,928 B
  hipFuncSetAttribute((const void*)edlstm_kernel,
                      hipFuncAttributeMaxDynamicSharedMemorySize, lds_bytes);
  edlstm_kernel<<<dim3(NB), dim3(NT), lds_bytes, stream>>>(
      x, eWih0, eWhh0, ebih0, ebhh0, eWih1, eWhh1, ebih1, ebhh1,
      dWih0, dWhh0, dbih0, dbhh0, dWih1, dWhh1, dbih1, dbhh1,
      fcW, fcb, out);
}

// Round 3
// 1566.027 us; speedup vs baseline: 6.9560x; 6.9560x over previous
//
#include <hip/hip_runtime.h>

// EncoderDecoderLSTM, round 3: split-bf16 (3-product) MFMA persistent kernel.
// 256 blocks x 512 threads (8 waves). Block owns 32 batch rows for all
// 336 enc + 168 dec steps. Weights as per-wave MFMA B-fragments in VGPRs
// (hi/lo bf16). h-state in LDS as bf16 hi/lo, XOR-swizzled 16B granules.
// gates: MFMA fp32 accs -> swizzled LDS -> pointwise threads (c in regs).

#define TT  336
#define HZN 168

typedef short s8v __attribute__((ext_vector_type(8)));
typedef short s4v __attribute__((ext_vector_type(4)));
typedef float f4v __attribute__((ext_vector_type(4)));

__device__ __forceinline__ float fexp(float v){
  return __builtin_amdgcn_exp2f(v * 1.44269504088896340736f);
}
__device__ __forceinline__ float sigm(float v){
  return __builtin_amdgcn_rcpf(1.0f + fexp(-v));
}
__device__ __forceinline__ float tanh_(float v){
  return 1.0f - 2.0f * __builtin_amdgcn_rcpf(1.0f + fexp(2.0f * v));
}

// round-to-nearest-even bf16 split: f ~= hi + lo
__device__ __forceinline__ void splitRNE(float f, short& hi, short& lo){
  unsigned u  = __float_as_uint(f);
  unsigned uh = u + 0x7fffu + ((u >> 16) & 1u);
  hi = (short)(uh >> 16);
  float fhi = __uint_as_float(uh & 0xffff0000u);
  float r   = f - fhi;
  unsigned v  = __float_as_uint(r);
  unsigned vh = v + 0x7fffu + ((v >> 16) & 1u);
  lo = (short)(vh >> 16);
}

// 3-product split-bf16 MFMA: c += A*B with A=ah+al, B=bh+bl (drop al*bl)
__device__ __forceinline__ f4v mm3(s8v ah, s8v al, s8v bh, s8v bl, f4v c){
  c = __builtin_amdgcn_mfma_f32_16x16x32_bf16(ah, bh, c, 0, 0, 0);
  c = __builtin_amdgcn_mfma_f32_16x16x32_bf16(ah, bl, c, 0, 0, 0);
  c = __builtin_amdgcn_mfma_f32_16x16x32_bf16(al, bh, c, 0, 0, 0);
  return c;
}

// read one A-fragment (8 bf16) from swizzled h LDS [32][64] shorts
__device__ __forceinline__ s8v ldA(const short* hb, int l, int mt, int kt){
  int row = mt*16 + (l & 15);
  int gr  = kt*4 + (l >> 4);
  return *(const s8v*)(hb + row*64 + ((gr ^ (row & 7)) << 3));
}

// load B-fragments of a [256][64] weight matrix for this wave's n-block
__device__ __forceinline__ void loadB(const float* __restrict__ Wm, int nb, int l,
                                      s8v Bh[2][2], s8v Bl[2][2]){
  #pragma unroll
  for (int nt=0; nt<2; nt++)
    #pragma unroll
    for (int kt=0; kt<2; kt++){
      int n  = nb + nt*16 + (l & 15);
      int k0 = kt*32 + ((l >> 4) << 3);
      const float* p = Wm + n*64 + k0;
      s8v vh, vl;
      #pragma unroll
      for (int j=0; j<8; j++){
        short hi, lo; splitRNE(p[j], hi, lo);
        vh[j] = hi; vl[j] = lo;
      }
      Bh[nt][kt] = vh; Bl[nt][kt] = vl;
    }
}

// write 4 accs (one (mt,nt) pair set) into swizzled fp32 g buffer [32][256]
__device__ __forceinline__ void stG(float* __restrict__ g, int l, int nb,
                                    const f4v acc[2][2]){
  #pragma unroll
  for (int mt=0; mt<2; mt++)
    #pragma unroll
    for (int nt=0; nt<2; nt++){
      int n = nb + nt*16 + (l & 15);
      #pragma unroll
      for (int r=0; r<4; r++){
        int row = mt*16 + ((l >> 4) << 2) + r;
        g[row*256 + (((n >> 2) ^ (row & 7)) << 2) + (n & 3)] = acc[mt][nt][r];
      }
    }
}

// pointwise LSTM update for 4 (row,col) elements; returns h, updates cv
template<bool USEX>
__device__ __forceinline__ f4v pointw(const float* __restrict__ g, int prow, int pc,
                                      f4v& cv, const f4v wx[4], float xv){
  f4v gv[4];
  #pragma unroll
  for (int T=0; T<4; T++){
    int gr = T*16 + (pc >> 2);
    gv[T] = *(const f4v*)(g + prow*256 + ((gr ^ (prow & 7)) << 2));
  }
  f4v h;
  #pragma unroll
  for (int j=0; j<4; j++){
    float gi = gv[0][j], gf = gv[1][j], gg = gv[2][j], go = gv[3][j];
    if (USEX){
      gi = fmaf(wx[0][j], xv, gi); gf = fmaf(wx[1][j], xv, gf);
      gg = fmaf(wx[2][j], xv, gg); go = fmaf(wx[3][j], xv, go);
    }
    float I = sigm(gi), F = sigm(gf), G = tanh_(gg), O = sigm(go);
    float cn = fmaf(F, cv[j], I*G);
    cv[j] = cn;
    h[j] = O * tanh_(cn);
  }
  return h;
}

// store 4 h elements as bf16 hi/lo into swizzled h LDS
__device__ __forceinline__ void stH(short* hhi, short* hlo, int prow, int pc, f4v h){
  s4v vh, vl;
  #pragma unroll
  for (int j=0; j<4; j++){
    short hi, lo; splitRNE(h[j], hi, lo);
    vh[j] = hi; vl[j] = lo;
  }
  int idx = prow*64 + ((((pc >> 3)) ^ (prow & 7)) << 3) + (pc & 7);
  *(s4v*)(hhi + idx) = vh;
  *(s4v*)(hlo + idx) = vl;
}

__global__ __launch_bounds__(512, 2)
void edlstm_kernel(const float* __restrict__ x,
  const float* __restrict__ eWih0, const float* __restrict__ eWhh0,
  const float* __restrict__ ebih0, const float* __restrict__ ebhh0,
  const float* __restrict__ eWih1, const float* __restrict__ eWhh1,
  const float* __restrict__ ebih1, const float* __restrict__ ebhh1,
  const float* __restrict__ dWih0, const float* __restrict__ dWhh0,
  const float* __restrict__ dbih0, const float* __restrict__ dbhh0,
  const float* __restrict__ dWih1, const float* __restrict__ dWhh1,
  const float* __restrict__ dbih1, const float* __restrict__ dbhh1,
  const float* __restrict__ fcW, const float* __restrict__ fcb,
  float* __restrict__ out)
{
  __shared__ s8v smem8[3072];            // 48 KB
  short* sb    = (short*)smem8;
  short* h0hi  = sb;                     // [32][64] swizzled
  short* h0lo  = sb + 2048;
  short* h1hi  = sb + 4096;
  short* h1lo  = sb + 6144;
  float* g     = (float*)(sb + 8192);    // [32][256] swizzled fp32

  const int tid = threadIdx.x;
  const int l   = tid & 63;
  const int w   = tid >> 6;
  const int nb  = w * 32;                // wave's n-block base (gate rows)
  const int prow = tid >> 4;             // pointwise row 0..31
  const int pc   = (tid & 15) * 4;       // pointwise col base
  const int brow0 = blockIdx.x * 32;

  // zero h state (first 8192 shorts = 1024 s8v)
  {
    s8v z = 0;
    #pragma unroll
    for (int i=0; i<2; i++) smem8[i*512 + tid] = z;
  }

  // per-lane biases (per nt) for acc init
  float bE0[2], bE1[2], bD0[2], bD1[2];
  #pragma unroll
  for (int nt=0; nt<2; nt++){
    int n = nb + nt*16 + (l & 15);
    bE0[nt] = ebih0[n] + ebhh0[n];
    bE1[nt] = ebih1[n] + ebhh1[n];
    bD0[nt] = dbih0[n] + dbhh0[n];
    bD1[nt] = dbih1[n] + dbhh1[n];
  }
  // pointwise consts: wx per (type, col) and fc weights
  f4v wxv[4];
  #pragma unroll
  for (int T=0; T<4; T++)
    wxv[T] = *(const f4v*)(eWih0 + T*64 + pc);
  f4v fcw = *(const f4v*)(fcW + pc);
  const float fcb0 = fcb[0];

  // encoder B-fragments (hi/lo) in VGPRs
  s8v Bhh0h[2][2], Bhh0l[2][2], Bih1h[2][2], Bih1l[2][2], Bhh1h[2][2], Bhh1l[2][2];
  loadB(eWhh0, nb, l, Bhh0h, Bhh0l);
  loadB(eWih1, nb, l, Bih1h, Bih1l);
  loadB(eWhh1, nb, l, Bhh1h, Bhh1l);

  f4v c0v = 0, c1v = 0;
  float xv = x[(size_t)(brow0 + prow) * TT];
  float xvn = 0.0f;
  __syncthreads();

  // ---------------- encoder ----------------
  for (int t=0; t<TT; t++){
    // L0: gates0 = bias + Whh0 . h0old   (x-part added in pointwise)
    f4v acc[2][2];
    #pragma unroll
    for (int mt=0; mt<2; mt++)
      #pragma unroll
      for (int nt=0; nt<2; nt++)
        acc[mt][nt] = f4v{bE0[nt], bE0[nt], bE0[nt], bE0[nt]};
    #pragma unroll
    for (int kt=0; kt<2; kt++){
      s8v a0h[2], a0l[2];
      #pragma unroll
      for (int mt=0; mt<2; mt++){
        a0h[mt] = ldA(h0hi, l, mt, kt);
        a0l[mt] = ldA(h0lo, l, mt, kt);
      }
      #pragma unroll
      for (int mt=0; mt<2; mt++)
        #pragma unroll
        for (int nt=0; nt<2; nt++)
          acc[mt][nt] = mm3(a0h[mt], a0l[mt], Bhh0h[nt][kt], Bhh0l[nt][kt], acc[mt][nt]);
    }
    stG(g, l, nb, acc);
    __syncthreads();                                   // bar1: g0 ready

    f4v h0v = pointw<true>(g, prow, pc, c0v, wxv, xv);
    stH(h0hi, h0lo, prow, pc, h0v);
    if (t+1 < TT) xvn = x[(size_t)(brow0 + prow) * TT + (t+1)];
    __syncthreads();                                   // bar2: h0new ready

    // L1: gates1 = bias + Wih1 . h0new + Whh1 . h1old
    #pragma unroll
    for (int mt=0; mt<2; mt++)
      #pragma unroll
      for (int nt=0; nt<2; nt++)
        acc[mt][nt] = f4v{bE1[nt], bE1[nt], bE1[nt], bE1[nt]};
    #pragma unroll
    for (int kt=0; kt<2; kt++){
      s8v a0h[2], a0l[2], a1h[2], a1l[2];
      #pragma unroll
      for (int mt=0; mt<2; mt++){
        a0h[mt] = ldA(h0hi, l, mt, kt);
        a0l[mt] = ldA(h0lo, l, mt, kt);
        a1h[mt] = ldA(h1hi, l, mt, kt);
        a1l[mt] = ldA(h1lo, l, mt, kt);
      }
      #pragma unroll
      for (int mt=0; mt<2; mt++)
        #pragma unroll
        for (int nt=0; nt<2; nt++){
          acc[mt][nt] = mm3(a0h[mt], a0l[mt], Bih1h[nt][kt], Bih1l[nt][kt], acc[mt][nt]);
          acc[mt][nt] = mm3(a1h[mt], a1l[mt], Bhh1h[nt][kt], Bhh1l[nt][kt], acc[mt][nt]);
        }
    }
    stG(g, l, nb, acc);
    __syncthreads();                                   // bar3: g1 ready

    f4v h1v = pointw<false>(g, prow, pc, c1v, wxv, 0.0f);
    stH(h1hi, h1lo, prow, pc, h1v);
    __syncthreads();                                   // bar4: h1new ready
    xv = xvn;
  }

  // decoder B-fragments (Whh0/Wih1/Whh1 arrays reused, Wih0 fresh)
  s8v Bih0h[2][2], Bih0l[2][2];
  loadB(dWih0, nb, l, Bih0h, Bih0l);
  loadB(dWhh0, nb, l, Bhh0h, Bhh0l);
  loadB(dWih1, nb, l, Bih1h, Bih1l);
  loadB(dWhh1, nb, l, Bhh1h, Bhh1l);

  // ---------------- decoder ----------------
  for (int s=0; s<HZN; s++){
    // L0: gates0 = bias + Wih0 . h1old(=xin, 0 at s=0) + Whh0 . h0old
    f4v acc[2][2];
    #pragma unroll
    for (int mt=0; mt<2; mt++)
      #pragma unroll
      for (int nt=0; nt<2; nt++)
        acc[mt][nt] = f4v{bD0[nt], bD0[nt], bD0[nt], bD0[nt]};
    #pragma unroll
    for (int kt=0; kt<2; kt++){
      s8v a0h[2], a0l[2];
      #pragma unroll
      for (int mt=0; mt<2; mt++){
        a0h[mt] = ldA(h0hi, l, mt, kt);
        a0l[mt] = ldA(h0lo, l, mt, kt);
      }
      #pragma unroll
      for (int mt=0; mt<2; mt++)
        #pragma unroll
        for (int nt=0; nt<2; nt++)
          acc[mt][nt] = mm3(a0h[mt], a0l[mt], Bhh0h[nt][kt], Bhh0l[nt][kt], acc[mt][nt]);
    }
    if (s > 0){
      #pragma unroll
      for (int kt=0; kt<2; kt++){
        s8v a1h[2], a1l[2];
        #pragma unroll
        for (int mt=0; mt<2; mt++){
          a1h[mt] = ldA(h1hi, l, mt, kt);
          a1l[mt] = ldA(h1lo, l, mt, kt);
        }
        #pragma unroll
        for (int mt=0; mt<2; mt++)
          #pragma unroll
          for (int nt=0; nt<2; nt++)
            acc[mt][nt] = mm3(a1h[mt], a1l[mt], Bih0h[nt][kt], Bih0l[nt][kt], acc[mt][nt]);
      }
    }
    stG(g, l, nb, acc);
    __syncthreads();                                   // bar1

    f4v h0v = pointw<false>(g, prow, pc, c0v, wxv, 0.0f);
    stH(h0hi, h0lo, prow, pc, h0v);
    __syncthreads();                                   // bar2

    // L1: gates1 = bias + Wih1 . h0new + Whh1 . h1old
    #pragma unroll
    for (int mt=0; mt<2; mt++)
      #pragma unroll
      for (int nt=0; nt<2; nt++)
        acc[mt][nt] = f4v{bD1[nt], bD1[nt], bD1[nt], bD1[nt]};
    #pragma unroll
    for (int kt=0; kt<2; kt++){
      s8v a0h[2], a0l[2], a1h[2], a1l[2];
      #pragma unroll
      for (int mt=0; mt<2; mt++){
        a0h[mt] = ldA(h0hi, l, mt, kt);
        a0l[mt] = ldA(h0lo, l, mt, kt);
        a1h[mt] = ldA(h1hi, l, mt, kt);
        a1l[mt] = ldA(h1lo, l, mt, kt);
      }
      #pragma unroll
      for (int mt=0; mt<2; mt++)
        #pragma unroll
        for (int nt=0; nt<2; nt++){
          acc[mt][nt] = mm3(a0h[mt], a0l[mt], Bih1h[nt][kt], Bih1l[nt][kt], acc[mt][nt]);
          acc[mt][nt] = mm3(a1h[mt], a1l[mt], Bhh1h[nt][kt], Bhh1l[nt][kt], acc[mt][nt]);
        }
    }
    stG(g, l, nb, acc);
    __syncthreads();                                   // bar3

    f4v h1v = pointw<false>(g, prow, pc, c1v, wxv, 0.0f);
    stH(h1hi, h1lo, prow, pc, h1v);
    // fc directly from registers: pred[row] = sum_c h1[row][c]*fcW[c] + fcb
    float pr = h1v[0]*fcw[0] + h1v[1]*fcw[1] + h1v[2]*fcw[2] + h1v[3]*fcw[3];
    pr += __shfl_xor(pr, 1); pr += __shfl_xor(pr, 2);
    pr += __shfl_xor(pr, 4); pr += __shfl_xor(pr, 8);
    if ((tid & 15) == 0)
      out[(size_t)(brow0 + prow) * HZN + s] = pr + fcb0;
    __syncthreads();                                   // bar4
  }
}

extern "C" void kernel_launch(void* const* d_in, const int* in_sizes, int n_in,
                              void* d_out, int out_size, void* d_ws, size_t ws_size,
                              hipStream_t stream)
{
  (void)in_sizes; (void)n_in; (void)d_ws; (void)ws_size; (void)out_size;
  const float* x     = (const float*)d_in[0];
  const float* eWih0 = (const float*)d_in[1];
  const float* eWhh0 = (const float*)d_in[2];
  const float* ebih0 = (const float*)d_in[3];
  const float* ebhh0 = (const float*)d_in[4];
  const float* eWih1 = (const float*)d_in[5];
  const float* eWhh1 = (const float*)d_in[6];
  const float* ebih1 = (const float*)d_in[7];
  const float* ebhh1 = (const float*)d_in[8];
  const float* dWih0 = (const float*)d_in[9];
  const float* dWhh0 = (const float*)d_in[10];
  const float* dbih0 = (const float*)d_in[11];
  const float* dbhh0 = (const float*)d_in[12];
  const float* dWih1 = (const float*)d_in[13];
  const float* dWhh1 = (const float*)d_in[14];
  const float* dbih1 = (const float*)d_in[15];
  const float* dbhh1 = (const float*)d_in[16];
  const float* fcW   = (const float*)d_in[17];
  const float* fcb   = (const float*)d_in[18];
  float* out = (float*)d_out;

  edlstm_kernel<<<dim3(256), dim3(512), 0, stream>>>(
      x, eWih0, eWhh0, ebih0, ebhh0, eWih1, eWhh1, ebih1, ebhh1,
      dWih0, dWhh0, dbih0, dbhh0, dWih1, dWhh1, dbih1, dbhh1,
      fcW, fcb, out);
}

// Round 4
// 1493.477 us; speedup vs baseline: 7.2939x; 1.0486x over previous
//
#include <hip/hip_runtime.h>

// EncoderDecoderLSTM, round 4: 2-product MFMA (h hi+lo x W-bf16), 512 blocks
// x 16 rows -> 2 blocks/CU so MFMA and pointwise phases overlap across blocks.
// Weights as per-wave B-fragments (bf16-hi only) in VGPRs; h in LDS bf16 hi/lo
// swizzled; gate ping-pong buffers g0/g1 (3 barriers/enc step, 4/dec step).

#define TT  336
#define HZN 168
#define NT  512
#define ROWS 16

typedef short s8v __attribute__((ext_vector_type(8)));
typedef short s2v __attribute__((ext_vector_type(2)));
typedef float f4v __attribute__((ext_vector_type(4)));
typedef float f2v __attribute__((ext_vector_type(2)));

__device__ __forceinline__ float fexp(float v){
  return __builtin_amdgcn_exp2f(v * 1.44269504088896340736f);
}
__device__ __forceinline__ float sigm(float v){
  return __builtin_amdgcn_rcpf(1.0f + fexp(-v));
}
__device__ __forceinline__ float tanh_(float v){
  return 1.0f - 2.0f * __builtin_amdgcn_rcpf(1.0f + fexp(2.0f * v));
}

__device__ __forceinline__ short bf16rne(float f){
  unsigned u = __float_as_uint(f);
  return (short)((u + 0x7fffu + ((u >> 16) & 1u)) >> 16);
}
// f ~= hi + lo (both bf16, RNE)
__device__ __forceinline__ void splitRNE(float f, short& hi, short& lo){
  hi = bf16rne(f);
  float fhi = __uint_as_float(((unsigned)(unsigned short)hi) << 16);
  lo = bf16rne(f - fhi);
}

// 2-product: c += (ah + al) * bh   (h fp32-exact, W bf16)
__device__ __forceinline__ f4v mm2(s8v ah, s8v al, s8v bh, f4v c){
  c = __builtin_amdgcn_mfma_f32_16x16x32_bf16(ah, bh, c, 0, 0, 0);
  c = __builtin_amdgcn_mfma_f32_16x16x32_bf16(al, bh, c, 0, 0, 0);
  return c;
}

// A-fragment (8 bf16) from swizzled h LDS [16][64] shorts
__device__ __forceinline__ s8v ldA(const short* hb, int l, int kt){
  int row = l & 15;
  int gr  = kt*4 + (l >> 4);
  return *(const s8v*)(hb + row*64 + ((gr ^ (row & 7)) << 3));
}

// B-fragments (bf16-hi) of a [256][64] weight matrix for this wave's n-block
__device__ __forceinline__ void loadBh(const float* __restrict__ Wm, int nb, int l,
                                       s8v Bh[2][2]){
  #pragma unroll
  for (int nt=0; nt<2; nt++)
    #pragma unroll
    for (int kt=0; kt<2; kt++){
      int n  = nb + nt*16 + (l & 15);
      int k0 = kt*32 + ((l >> 4) << 3);
      const float* p = Wm + n*64 + k0;
      float4 q0 = *(const float4*)(p);
      float4 q1 = *(const float4*)(p + 4);
      s8v vh;
      vh[0]=bf16rne(q0.x); vh[1]=bf16rne(q0.y); vh[2]=bf16rne(q0.z); vh[3]=bf16rne(q0.w);
      vh[4]=bf16rne(q1.x); vh[5]=bf16rne(q1.y); vh[6]=bf16rne(q1.z); vh[7]=bf16rne(q1.w);
      Bh[nt][kt] = vh;
    }
}

// write accs into swizzled fp32 gate buffer [16][256]
__device__ __forceinline__ void stG(float* __restrict__ g, int l, int nb,
                                    const f4v acc[2]){
  #pragma unroll
  for (int nt=0; nt<2; nt++){
    int n = nb + nt*16 + (l & 15);
    #pragma unroll
    for (int r=0; r<4; r++){
      int row = ((l >> 4) << 2) + r;
      g[row*256 + (((n >> 2) ^ (row & 7)) << 2) + (n & 3)] = acc[nt][r];
    }
  }
}

// pointwise LSTM update for 2 (row,col) elements
template<bool USEX>
__device__ __forceinline__ f2v pointw(const float* __restrict__ g,
                                      const float* __restrict__ wxs, float xv,
                                      int prow, int pcol, f2v& cv){
  f2v gv[4];
  #pragma unroll
  for (int T=0; T<4; T++){
    int gr = T*16 + (pcol >> 2);
    gv[T] = *(const f2v*)(g + prow*256 + ((gr ^ (prow & 7)) << 2) + (pcol & 3));
  }
  f2v wv[4];
  if (USEX){
    #pragma unroll
    for (int T=0; T<4; T++)
      wv[T] = *(const f2v*)(wxs + T*64 + pcol);
  }
  f2v h;
  #pragma unroll
  for (int j=0; j<2; j++){
    float gi = gv[0][j], gf = gv[1][j], gg = gv[2][j], go = gv[3][j];
    if (USEX){
      gi = fmaf(wv[0][j], xv, gi); gf = fmaf(wv[1][j], xv, gf);
      gg = fmaf(wv[2][j], xv, gg); go = fmaf(wv[3][j], xv, go);
    }
    float I = sigm(gi), F = sigm(gf), G = tanh_(gg), O = sigm(go);
    float cn = fmaf(F, cv[j], I*G);
    cv[j] = cn;
    h[j] = O * tanh_(cn);
  }
  return h;
}

// store 2 h elements as bf16 hi/lo into swizzled h LDS
__device__ __forceinline__ void stH(short* hhi, short* hlo, int prow, int pcol, f2v h){
  s2v vh, vl;
  #pragma unroll
  for (int j=0; j<2; j++){
    short hi, lo; splitRNE(h[j], hi, lo);
    vh[j] = hi; vl[j] = lo;
  }
  int idx = prow*64 + (((pcol >> 3) ^ (prow & 7)) << 3) + (pcol & 7);
  *(s2v*)(hhi + idx) = vh;
  *(s2v*)(hlo + idx) = vl;
}

__global__ __launch_bounds__(NT, 4)
void edlstm_kernel(const float* __restrict__ x,
  const float* __restrict__ eWih0, const float* __restrict__ eWhh0,
  const float* __restrict__ ebih0, const float* __restrict__ ebhh0,
  const float* __restrict__ eWih1, const float* __restrict__ eWhh1,
  const float* __restrict__ ebih1, const float* __restrict__ ebhh1,
  const float* __restrict__ dWih0, const float* __restrict__ dWhh0,
  const float* __restrict__ dbih0, const float* __restrict__ dbhh0,
  const float* __restrict__ dWih1, const float* __restrict__ dWhh1,
  const float* __restrict__ dbih1, const float* __restrict__ dbhh1,
  const float* __restrict__ fcW, const float* __restrict__ fcb,
  float* __restrict__ out)
{
  __shared__ short h0hi[ROWS*64], h0lo[ROWS*64], h1hi[ROWS*64], h1lo[ROWS*64];
  __shared__ float g0[ROWS*256], g1[ROWS*256];
  __shared__ float xs[ROWS*TT];
  __shared__ float wxs[256];

  const int tid  = threadIdx.x;
  const int l    = tid & 63;
  const int w    = tid >> 6;
  const int nb   = w * 32;            // wave's gate-row block base (0..224)
  const int prow = tid >> 5;          // pointwise row 0..15
  const int pcol = (tid & 31) * 2;    // pointwise col base (even)
  const int brow0 = blockIdx.x * ROWS;

  // ---- prologue ----
  { // zero h buffers (4 x 1024 shorts = 2048 dwords, contiguous)
    int* hz = (int*)h0hi;
    #pragma unroll
    for (int k=0; k<4; k++) hz[k*NT + tid] = 0;
  }
  #pragma unroll
  for (int k=0; k<3; k++){            // stage x: 16 rows x 84 float4
    int idx = k*NT + tid;
    if (idx < ROWS*84){
      int row = idx / 84;
      int c   = idx - row*84;
      *(float4*)(xs + row*TT + c*4) =
        *(const float4*)(x + (size_t)(brow0+row)*TT + c*4);
    }
  }
  if (tid < 256) wxs[tid] = eWih0[tid];

  float bE0[2], bE1[2], bD0[2], bD1[2];
  #pragma unroll
  for (int nt=0; nt<2; nt++){
    int n = nb + nt*16 + (l & 15);
    bE0[nt] = ebih0[n] + ebhh0[n];
    bE1[nt] = ebih1[n] + ebhh1[n];
    bD0[nt] = dbih0[n] + dbhh0[n];
    bD1[nt] = dbih1[n] + dbhh1[n];
  }
  f2v fcw = *(const f2v*)(fcW + pcol);
  const float fcb0 = fcb[0];

  // encoder B-fragments
  s8v Bhh0[2][2], Bih1[2][2], Bhh1[2][2];
  loadBh(eWhh0, nb, l, Bhh0);
  loadBh(eWih1, nb, l, Bih1);
  loadBh(eWhh1, nb, l, Bhh1);

  f2v c0 = {0.f, 0.f}, c1 = {0.f, 0.f};
  __syncthreads();

  // ---------------- encoder: 336 steps ----------------
  for (int t=0; t<TT; t++){
    // L0: g0 = bias + Whh0 . h0old  (x-part added in pointwise)
    f4v acc[2];
    #pragma unroll
    for (int nt=0; nt<2; nt++) acc[nt] = f4v{bE0[nt],bE0[nt],bE0[nt],bE0[nt]};
    #pragma unroll
    for (int kt=0; kt<2; kt++){
      s8v ah = ldA(h0hi, l, kt);
      s8v al = ldA(h0lo, l, kt);
      #pragma unroll
      for (int nt=0; nt<2; nt++) acc[nt] = mm2(ah, al, Bhh0[nt][kt], acc[nt]);
    }
    stG(g0, l, nb, acc);
    __syncthreads();                               // bar1: g0 ready

    float xv = xs[prow*TT + t];
    f2v h0v = pointw<true>(g0, wxs, xv, prow, pcol, c0);
    stH(h0hi, h0lo, prow, pcol, h0v);
    __syncthreads();                               // bar2: h0new ready

    // L1: g1 = bias + Wih1 . h0new + Whh1 . h1old
    #pragma unroll
    for (int nt=0; nt<2; nt++) acc[nt] = f4v{bE1[nt],bE1[nt],bE1[nt],bE1[nt]};
    #pragma unroll
    for (int kt=0; kt<2; kt++){
      s8v a0h = ldA(h0hi, l, kt);
      s8v a0l = ldA(h0lo, l, kt);
      s8v a1h = ldA(h1hi, l, kt);
      s8v a1l = ldA(h1lo, l, kt);
      #pragma unroll
      for (int nt=0; nt<2; nt++){
        acc[nt] = mm2(a0h, a0l, Bih1[nt][kt], acc[nt]);
        acc[nt] = mm2(a1h, a1l, Bhh1[nt][kt], acc[nt]);
      }
    }
    stG(g1, l, nb, acc);
    __syncthreads();                               // bar3: g1 ready

    f2v h1v = pointw<false>(g1, wxs, 0.f, prow, pcol, c1);
    stH(h1hi, h1lo, prow, pcol, h1v);
    // no barrier: h1 next read (L1 of t+1) is >= 2 barriers away; g0/h0 disjoint
  }

  // decoder B-fragments
  s8v Dih0[2][2];
  loadBh(dWih0, nb, l, Dih0);
  loadBh(dWhh0, nb, l, Bhh0);
  loadBh(dWih1, nb, l, Bih1);
  loadBh(dWhh1, nb, l, Bhh1);

  // ---------------- decoder: 168 steps ----------------
  for (int s=0; s<HZN; s++){
    // L0: g0 = bias + Whh0 . h0old + (s>0) Wih0 . h1old
    f4v acc[2];
    #pragma unroll
    for (int nt=0; nt<2; nt++) acc[nt] = f4v{bD0[nt],bD0[nt],bD0[nt],bD0[nt]};
    #pragma unroll
    for (int kt=0; kt<2; kt++){
      s8v ah = ldA(h0hi, l, kt);
      s8v al = ldA(h0lo, l, kt);
      #pragma unroll
      for (int nt=0; nt<2; nt++) acc[nt] = mm2(ah, al, Bhh0[nt][kt], acc[nt]);
    }
    if (s > 0){
      #pragma unroll
      for (int kt=0; kt<2; kt++){
        s8v ah = ldA(h1hi, l, kt);
        s8v al = ldA(h1lo, l, kt);
        #pragma unroll
        for (int nt=0; nt<2; nt++) acc[nt] = mm2(ah, al, Dih0[nt][kt], acc[nt]);
      }
    }
    stG(g0, l, nb, acc);
    __syncthreads();                               // bar1

    f2v h0v = pointw<false>(g0, wxs, 0.f, prow, pcol, c0);
    stH(h0hi, h0lo, prow, pcol, h0v);
    __syncthreads();                               // bar2

    // L1: g1 = bias + Wih1 . h0new + Whh1 . h1old
    #pragma unroll
    for (int nt=0; nt<2; nt++) acc[nt] = f4v{bD1[nt],bD1[nt],bD1[nt],bD1[nt]};
    #pragma unroll
    for (int kt=0; kt<2; kt++){
      s8v a0h = ldA(h0hi, l, kt);
      s8v a0l = ldA(h0lo, l, kt);
      s8v a1h = ldA(h1hi, l, kt);
      s8v a1l = ldA(h1lo, l, kt);
      #pragma unroll
      for (int nt=0; nt<2; nt++){
        acc[nt] = mm2(a0h, a0l, Bih1[nt][kt], acc[nt]);
        acc[nt] = mm2(a1h, a1l, Bhh1[nt][kt], acc[nt]);
      }
    }
    stG(g1, l, nb, acc);
    __syncthreads();                               // bar3

    f2v h1v = pointw<false>(g1, wxs, 0.f, prow, pcol, c1);
    stH(h1hi, h1lo, prow, pcol, h1v);

    // fc: pred[row] = sum_col h1 * fcW + fcb   (reduce 32 lanes = 64 cols)
    float p = h1v[0]*fcw[0] + h1v[1]*fcw[1];
    p += __shfl_xor(p, 1);  p += __shfl_xor(p, 2);
    p += __shfl_xor(p, 4);  p += __shfl_xor(p, 8);
    p += __shfl_xor(p, 16);
    if ((tid & 31) == 0)
      out[(size_t)(brow0 + prow)*HZN + s] = p + fcb0;
    __syncthreads();                               // bar4: h1new before next L0 read
  }
}

extern "C" void kernel_launch(void* const* d_in, const int* in_sizes, int n_in,
                              void* d_out, int out_size, void* d_ws, size_t ws_size,
                              hipStream_t stream)
{
  (void)in_sizes; (void)n_in; (void)d_ws; (void)ws_size; (void)out_size;
  const float* x     = (const float*)d_in[0];
  const float* eWih0 = (const float*)d_in[1];
  const float* eWhh0 = (const float*)d_in[2];
  const float* ebih0 = (const float*)d_in[3];
  const float* ebhh0 = (const float*)d_in[4];
  const float* eWih1 = (const float*)d_in[5];
  const float* eWhh1 = (const float*)d_in[6];
  const float* ebih1 = (const float*)d_in[7];
  const float* ebhh1 = (const float*)d_in[8];
  const float* dWih0 = (const float*)d_in[9];
  const float* dWhh0 = (const float*)d_in[10];
  const float* dbih0 = (const float*)d_in[11];
  const float* dbhh0 = (const float*)d_in[12];
  const float* dWih1 = (const float*)d_in[13];
  const float* dWhh1 = (const float*)d_in[14];
  const float* dbih1 = (const float*)d_in[15];
  const float* dbhh1 = (const float*)d_in[16];
  const float* fcW   = (const float*)d_in[17];
  const float* fcb   = (const float*)d_in[18];
  float* out = (float*)d_out;

  edlstm_kernel<<<dim3(512), dim3(NT), 0, stream>>>(
      x, eWih0, eWhh0, ebih0, ebhh0, eWih1, eWhh1, ebih1, ebhh1,
      dWih0, dWhh0, dbih0, dbhh0, dWih1, dWhh1, dbih1, dbhh1,
      fcW, fcb, out);
}